// Round 12
// baseline (1530.441 us; speedup 1.0000x reference)
//
#include <hip/hip_runtime.h>
#include <hip/hip_bf16.h>

// Round 15: gemm_lstm redesign — 128x64h tile (192 gate-cols, 2x MFMA
// density per step), uniform 5 loads/step with counted vmcnt(5) (verified
// R14 template), and conflict-free LDS chunk swizzle pos=lq^((row>>1)&3)
// (pre-swizzled global source, linear LDS dest). Other kernels = R14.

typedef __hip_bfloat16 bf16;
typedef __attribute__((ext_vector_type(8))) short short8;
typedef __attribute__((ext_vector_type(4))) float f32x4;

__device__ __forceinline__ float bf2f(bf16 x){ return __bfloat162float(x); }
__device__ __forceinline__ bf16  f2bf(float x){ return __float2bfloat16(x); }

__device__ __forceinline__ void gld16(const bf16* g, bf16* l){
  __builtin_amdgcn_global_load_lds(
      (const __attribute__((address_space(1))) void*)g,
      (__attribute__((address_space(3))) void*)l, 16, 0, 0);
}

__device__ __forceinline__ void barrier_raw(){ asm volatile("s_barrier" ::: "memory"); }
__device__ __forceinline__ void wait_vm0(){ asm volatile("s_waitcnt vmcnt(0)" ::: "memory"); }
__device__ __forceinline__ void wait_vm5(){ asm volatile("s_waitcnt vmcnt(5)" ::: "memory"); }

__device__ __forceinline__ float sigm(float x){ return 1.0f/(1.0f + __expf(-x)); }
__device__ __forceinline__ float tanhfast(float x){
  x = fminf(fmaxf(x, -15.f), 15.f);
  float e = __expf(2.f*x);
  return (e-1.f)/(e+1.f);
}

// ---------------------------------------------------------------------------
// Batched fp32 -> bf16 weight conversion into arena.
// ---------------------------------------------------------------------------
struct CvtPtrs { const float* p[25]; };
__constant__ long CVT_CUM[26] = {0, 98304, 98432, 360576, 360704, 426240,
  426368, 1450368, 1452368, 2476368, 2478368, 3502368, 3504368, 3760368,
  3760496, 4784496, 4786496, 5786496, 5786996, 6042996, 6043124, 7067124,
  7069124, 8069124, 8069624, 8070624};

__global__ __launch_bounds__(256) void cvt_all(CvtPtrs P, bf16* __restrict__ arena)
{
  long g = (long)blockIdx.x * 256 + threadIdx.x;
  if (g >= 8070624l) return;
  int lo = 0, hi = 24;
  while (lo < hi) { int mid = (lo + hi + 1) >> 1; if (g >= CVT_CUM[mid]) lo = mid; else hi = mid - 1; }
  long rel = (g - CVT_CUM[lo]) * 4;
  float4 v = *(const float4*)(P.p[lo] + rel);
  union { bf16 h[4]; uint2 u; } t;
  t.h[0]=f2bf(v.x); t.h[1]=f2bf(v.y); t.h[2]=f2bf(v.z); t.h[3]=f2bf(v.w);
  *(uint2*)(arena + CVT_CUM[lo]*4 + rel) = t.u;
}

// ---------------------------------------------------------------------------
// bt-GEMM, fp32 A / bf16 B: C = A @ Bt^T + bias (bf16 out). 128x128, BK=32.
// 2-phase double-buffered. Segmented A (splitx). K%32==0, gridDim.x*128==M.
// ---------------------------------------------------------------------------
__global__ __launch_bounds__(256) void gemm_linA32(
    const float* __restrict__ A, const float* __restrict__ A2, int splitx,
    const bf16* __restrict__ Bt, const bf16* __restrict__ bias,
    bf16* __restrict__ C, int M, int N, int K, int lda, int ldb, int ldc)
{
  __shared__ bf16 sm[2][(128+128)*32];
  const int tid  = threadIdx.x;
  const int wave = tid >> 6, lane = tid & 63;
  const int wr = (wave >> 1) * 64, wc = (wave & 1) * 64;
  const int ln = lane & 15, lq = lane >> 4;
  const long m0 = (long)blockIdx.x * 128;           // global output row base
  const int  n0 = blockIdx.y * 128;

  const float* Abase; long mrow;
  if ((int)blockIdx.x < splitx) { Abase = A;  mrow = m0; }
  else { Abase = A2; mrow = (long)((int)blockIdx.x - splitx) * 128; }

  const int arow = tid >> 1, ahalf = (tid & 1) * 16;
  const float* pA = Abase + (mrow + arow) * (long)lda + ahalf;
  const int sAoff = arow * 32 + ahalf;              // elements into As
  const int ch = (tid & 3) * 8;
  int colA = n0 + (tid >> 2);       colA = (colA < N) ? colA : (N - 1);
  int colB = n0 + (tid >> 2) + 64;  colB = (colB < N) ? colB : (N - 1);
  const bf16* pB0 = Bt + (long)colA * ldb + ch;
  const bf16* pB1 = Bt + (long)colB * ldb + ch;
  const int sB0 = 128*32 + tid * 8, sB1 = 128*32 + (tid + 256) * 8;

  auto cvtA = [&](bf16* dst, float4 v0, float4 v1, float4 v2, float4 v3){
    union { bf16 h[16]; short8 q[2]; } u;
    u.h[0]=f2bf(v0.x); u.h[1]=f2bf(v0.y); u.h[2]=f2bf(v0.z); u.h[3]=f2bf(v0.w);
    u.h[4]=f2bf(v1.x); u.h[5]=f2bf(v1.y); u.h[6]=f2bf(v1.z); u.h[7]=f2bf(v1.w);
    u.h[8]=f2bf(v2.x); u.h[9]=f2bf(v2.y); u.h[10]=f2bf(v2.z); u.h[11]=f2bf(v2.w);
    u.h[12]=f2bf(v3.x); u.h[13]=f2bf(v3.y); u.h[14]=f2bf(v3.z); u.h[15]=f2bf(v3.w);
    *(short8*)(dst)     = u.q[0];
    *(short8*)(dst + 8) = u.q[1];
  };

  const int ksteps = K >> 5;
  { // prologue: stage tile 0 into buffer 0
    float4 v0 = *(const float4*)(pA);
    float4 v1 = *(const float4*)(pA + 4);
    float4 v2 = *(const float4*)(pA + 8);
    float4 v3 = *(const float4*)(pA + 12);
    cvtA(sm[0] + sAoff, v0, v1, v2, v3);
    gld16(pB0, sm[0] + sB0);
    gld16(pB1, sm[0] + sB1);
    pA += 32; pB0 += 32; pB1 += 32;
  }
  __syncthreads();

  f32x4 acc[4][4] = {};
  for (int ks = 0; ks < ksteps; ++ks) {
    const bf16* S = sm[ks & 1];
    bf16* Sn = sm[(ks + 1) & 1];
    const bool stage = (ks + 1 < ksteps);
    float4 v0, v1, v2, v3;
    if (stage) {
      v0 = *(const float4*)(pA);
      v1 = *(const float4*)(pA + 4);
      v2 = *(const float4*)(pA + 8);
      v3 = *(const float4*)(pA + 12);
      gld16(pB0, Sn + sB0);
      gld16(pB1, Sn + sB1);
      pA += 32; pB0 += 32; pB1 += 32;
    }
    const bf16* As = S; const bf16* Bs = S + 128*32;
    short8 af[4], bv[4];
#pragma unroll
    for (int i = 0; i < 4; ++i)
      af[i] = *(const short8*)(As + (wr + i*16 + ln) * 32 + lq * 8);
#pragma unroll
    for (int j = 0; j < 4; ++j)
      bv[j] = *(const short8*)(Bs + (wc + j*16 + ln) * 32 + lq * 8);
#pragma unroll
    for (int i = 0; i < 4; ++i)
#pragma unroll
      for (int j = 0; j < 4; ++j)
        acc[i][j] = __builtin_amdgcn_mfma_f32_16x16x32_bf16(af[i], bv[j], acc[i][j], 0, 0, 0);
    if (stage) cvtA(Sn + sAoff, v0, v1, v2, v3);
    __syncthreads();
  }
#pragma unroll
  for (int j = 0; j < 4; ++j) {
    int n = n0 + wc + j * 16 + ln;
    if (n < N) {
      float bvv = bf2f(bias[n]);
#pragma unroll
      for (int i = 0; i < 4; ++i)
#pragma unroll
        for (int r = 0; r < 4; ++r) {
          long m = m0 + wr + i * 16 + lq * 4 + r;
          C[m * ldc + n] = f2bf(acc[i][j][r] + bvv);
        }
    } else if (n < ldc) {
#pragma unroll
      for (int i = 0; i < 4; ++i)
#pragma unroll
        for (int r = 0; r < 4; ++r) {
          long m = m0 + wr + i * 16 + lq * 4 + r;
          C[m * ldc + n] = f2bf(0.f);
        }
    }
  }
}

// ---------------------------------------------------------------------------
// bt-GEMM, bf16 A / bf16 B, bf16 out. 2-phase double-buffered.
// A zero-padded over [K, 32*ceil(K/32)). B overreads <=16 elems hit A-zeros.
// ---------------------------------------------------------------------------
__global__ __launch_bounds__(256) void gemm_lin(
    const bf16* __restrict__ A, const bf16* __restrict__ Bt,
    const bf16* __restrict__ bias, bf16* __restrict__ C,
    int M, int N, int K, int lda, int ldb, int ldc)
{
  __shared__ bf16 sm[2][(128+128)*32];
  const int tid  = threadIdx.x;
  const int wave = tid >> 6, lane = tid & 63;
  const int wr = (wave >> 1) * 64, wc = (wave & 1) * 64;
  const int ln = lane & 15, lq = lane >> 4;
  const long m0 = (long)blockIdx.x * 128;
  const int  n0 = blockIdx.y * 128;

  const int ch = (tid & 3) * 8;
  const bf16* pA0 = A + (m0 + (tid >> 2)) * (long)lda + ch;
  const bf16* pA1 = A + (m0 + (tid >> 2) + 64) * (long)lda + ch;
  int colA = n0 + (tid >> 2);       colA = (colA < N) ? colA : (N - 1);
  int colB = n0 + (tid >> 2) + 64;  colB = (colB < N) ? colB : (N - 1);
  const bf16* pB0 = Bt + (long)colA * ldb + ch;
  const bf16* pB1 = Bt + (long)colB * ldb + ch;
  const int sA0 = tid * 8, sA1 = (tid + 256) * 8;
  const int sB0 = 128*32 + tid * 8, sB1 = 128*32 + (tid + 256) * 8;

  const int ksteps = (K + 31) >> 5;
  {
    gld16(pA0, sm[0] + sA0); gld16(pA1, sm[0] + sA1);
    gld16(pB0, sm[0] + sB0); gld16(pB1, sm[0] + sB1);
    pA0 += 32; pA1 += 32; pB0 += 32; pB1 += 32;
  }
  __syncthreads();

  f32x4 acc[4][4] = {};
  for (int ks = 0; ks < ksteps; ++ks) {
    const bf16* S = sm[ks & 1];
    bf16* Sn = sm[(ks + 1) & 1];
    if (ks + 1 < ksteps) {
      gld16(pA0, Sn + sA0); gld16(pA1, Sn + sA1);
      gld16(pB0, Sn + sB0); gld16(pB1, Sn + sB1);
      pA0 += 32; pA1 += 32; pB0 += 32; pB1 += 32;
    }
    const bf16* As = S; const bf16* Bs = S + 128*32;
    short8 af[4], bv[4];
#pragma unroll
    for (int i = 0; i < 4; ++i)
      af[i] = *(const short8*)(As + (wr + i*16 + ln) * 32 + lq * 8);
#pragma unroll
    for (int j = 0; j < 4; ++j)
      bv[j] = *(const short8*)(Bs + (wc + j*16 + ln) * 32 + lq * 8);
#pragma unroll
    for (int i = 0; i < 4; ++i)
#pragma unroll
      for (int j = 0; j < 4; ++j)
        acc[i][j] = __builtin_amdgcn_mfma_f32_16x16x32_bf16(af[i], bv[j], acc[i][j], 0, 0, 0);
    __syncthreads();
  }
#pragma unroll
  for (int j = 0; j < 4; ++j) {
    int n = n0 + wc + j * 16 + ln;
    if (n < N) {
      float bvv = bf2f(bias[n]);
#pragma unroll
      for (int i = 0; i < 4; ++i)
#pragma unroll
        for (int r = 0; r < 4; ++r) {
          long m = m0 + wr + i * 16 + lq * 4 + r;
          C[m * ldc + n] = f2bf(acc[i][j][r] + bvv);
        }
    } else if (n < ldc) {
#pragma unroll
      for (int i = 0; i < 4; ++i)
#pragma unroll
        for (int r = 0; r < 4; ++r) {
          long m = m0 + wr + i * 16 + lq * 4 + r;
          C[m * ldc + n] = f2bf(0.f);
        }
    }
  }
}

// ---------------------------------------------------------------------------
// Merged agg out-GEMM, fp32 out, 2-phase double-buffered. Two 512x2000x2000
// problems: grid (8,16); blocks 0..3 -> seg0, 4..7 -> seg1.
// ---------------------------------------------------------------------------
__global__ __launch_bounds__(256) void gemm_out_f32(
    const bf16* __restrict__ A0, const bf16* __restrict__ A1,
    const bf16* __restrict__ B0, const bf16* __restrict__ B1,
    const bf16* __restrict__ b0, const bf16* __restrict__ b1,
    float* __restrict__ C0, float* __restrict__ C1)
{
  __shared__ bf16 sm[2][(128+128)*32];
  const int tid  = threadIdx.x;
  const int wave = tid >> 6, lane = tid & 63;
  const int wr = (wave >> 1) * 64, wc = (wave & 1) * 64;
  const int ln = lane & 15, lq = lane >> 4;
  const int seg = blockIdx.x >> 2;
  const long m0 = (long)(blockIdx.x & 3) * 128;
  const int  n0 = blockIdx.y * 128;
  const int N = 2000, lda = 2016, ldb = 2000, ldc = 2000;

  const bf16* A    = seg ? A1 : A0;
  const bf16* Bt   = seg ? B1 : B0;
  const bf16* bias = seg ? b1 : b0;
  float*      C    = seg ? C1 : C0;

  const int ch = (tid & 3) * 8;
  const bf16* pA0 = A + (m0 + (tid >> 2)) * (long)lda + ch;
  const bf16* pA1 = A + (m0 + (tid >> 2) + 64) * (long)lda + ch;
  int colA = n0 + (tid >> 2);       colA = (colA < N) ? colA : (N - 1);
  int colB = n0 + (tid >> 2) + 64;  colB = (colB < N) ? colB : (N - 1);
  const bf16* pB0 = Bt + (long)colA * ldb + ch;
  const bf16* pB1 = Bt + (long)colB * ldb + ch;
  const int sA0 = tid * 8, sA1 = (tid + 256) * 8;
  const int sB0 = 128*32 + tid * 8, sB1 = 128*32 + (tid + 256) * 8;

  {
    gld16(pA0, sm[0] + sA0); gld16(pA1, sm[0] + sA1);
    gld16(pB0, sm[0] + sB0); gld16(pB1, sm[0] + sB1);
    pA0 += 32; pA1 += 32; pB0 += 32; pB1 += 32;
  }
  __syncthreads();

  f32x4 acc[4][4] = {};
  for (int ks = 0; ks < 63; ++ks) {          // K = 2000 -> 63 steps of 32
    const bf16* S = sm[ks & 1];
    bf16* Sn = sm[(ks + 1) & 1];
    if (ks + 1 < 63) {
      gld16(pA0, Sn + sA0); gld16(pA1, Sn + sA1);
      gld16(pB0, Sn + sB0); gld16(pB1, Sn + sB1);
      pA0 += 32; pA1 += 32; pB0 += 32; pB1 += 32;
    }
    const bf16* As = S; const bf16* Bs = S + 128*32;
    short8 af[4], bv[4];
#pragma unroll
    for (int i = 0; i < 4; ++i)
      af[i] = *(const short8*)(As + (wr + i*16 + ln) * 32 + lq * 8);
#pragma unroll
    for (int j = 0; j < 4; ++j)
      bv[j] = *(const short8*)(Bs + (wc + j*16 + ln) * 32 + lq * 8);
#pragma unroll
    for (int i = 0; i < 4; ++i)
#pragma unroll
      for (int j = 0; j < 4; ++j)
        acc[i][j] = __builtin_amdgcn_mfma_f32_16x16x32_bf16(af[i], bv[j], acc[i][j], 0, 0, 0);
    __syncthreads();
  }
#pragma unroll
  for (int j = 0; j < 4; ++j) {
    int n = n0 + wc + j * 16 + ln;
    if (n < N) {
      float bvv = bf2f(bias[n]);
#pragma unroll
      for (int i = 0; i < 4; ++i)
#pragma unroll
        for (int r = 0; r < 4; ++r) {
          long m = m0 + wr + i * 16 + lq * 4 + r;
          C[m * ldc + n] = acc[i][j][r] + bvv;
        }
    }
  }
}

// ---------------------------------------------------------------------------
// Fused single-step BiLSTM gate GEMM + activation (f-gate dead; h0=c0=0).
// Tile 128 rows x 64 h-cols (192 gate-cols). Counted vmcnt(5) + raw
// s_barrier (verified R14 template; 5 uniform loads/thread/step).
// LDS chunk swizzle pos = lq ^ ((row>>1)&3): staging loads pre-swizzled
// global chunk, LDS dest linear (gld16-safe); reads add per-lane-const swz.
// ---------------------------------------------------------------------------
__global__ __launch_bounds__(256) void gemm_lstm(
    const bf16* __restrict__ A, const bf16* __restrict__ W,
    const bf16* __restrict__ bvec, const bf16* __restrict__ other,
    bf16* __restrict__ Hout, int ldo, int ldc, int combine)
{
  __shared__ bf16 sm[2][(128+192)*32];
  const int tid  = threadIdx.x;
  const int wave = tid >> 6, lane = tid & 63;
  const int wr = (wave >> 1) * 64, wc = (wave & 1) * 96;
  const int ln = lane & 15, lq = lane >> 4;
  const long m0 = (long)blockIdx.x * 128;
  const int dir = blockIdx.y >> 4, jb = blockIdx.y & 15;

  // pre-swizzled chunk for staging: slot (row=s>>2, pos=s&3) receives
  // global chunk pos ^ ((row>>1)&3). All 5 slots of this thread share
  // (row>>1)&3 == (tid>>3)&3 (slot rows differ by multiples of 64).
  const int ch = (((tid & 3) ^ ((tid >> 3) & 3))) * 8;
  const bf16* pA0 = A + (m0 + (tid >> 2)) * 512 + ch;
  const bf16* pA1 = A + (m0 + (tid >> 2) + 64) * 512 + ch;
  auto brow = [&](int t) -> long {
    int tc = t >> 2;                   // B-tile row 0..191
    int g48 = tc / 48, wi = tc % 48;
    int cf = wi >> 4;                  // gate 0,1,2 -> I,G,O
    int jj = jb * 64 + g48 * 16 + (wi & 15);
    jj = (jj < 1000) ? jj : 999;
    return (long)(dir * 4000 + (cf ? (cf + 1) * 1000 : 0) + jj);
  };
  const bf16* pB0 = W + brow(tid) * 512 + ch;
  const bf16* pB1 = W + brow(tid + 256) * 512 + ch;
  const bf16* pB2 = W + brow(tid + 512) * 512 + ch;
  const int sA0 = tid * 8, sA1 = (tid + 256) * 8;
  const int sB0 = 128*32 + tid * 8;
  const int sB1 = 128*32 + (tid + 256) * 8;
  const int sB2 = 128*32 + (tid + 512) * 8;
  // read-side swizzle: row = (mult of 16) + ln -> (row>>1)&3 == (ln>>1)&3
  const int swz = (lq ^ ((ln >> 1) & 3)) * 8;

  { // prologue: stage tile 0 (stays in flight; loop's vmcnt+barrier syncs)
    gld16(pA0, sm[0] + sA0); gld16(pA1, sm[0] + sA1);
    gld16(pB0, sm[0] + sB0); gld16(pB1, sm[0] + sB1); gld16(pB2, sm[0] + sB2);
    pA0 += 32; pA1 += 32; pB0 += 32; pB1 += 32; pB2 += 32;
  }

  f32x4 acc[4][6] = {};
  for (int ks = 0; ks < 16; ++ks) {          // K = 512
    const bf16* S = sm[ks & 1];
    bf16* Sn = sm[(ks + 1) & 1];
    const bool stage = (ks + 1 < 16);
    if (stage) {
      gld16(pA0, Sn + sA0); gld16(pA1, Sn + sA1);
      gld16(pB0, Sn + sB0); gld16(pB1, Sn + sB1); gld16(pB2, Sn + sB2);
      pA0 += 32; pA1 += 32; pB0 += 32; pB1 += 32; pB2 += 32;
    }
    // wait only for tile-ks loads; tile-(ks+1) loads stay in flight
    if (stage) wait_vm5(); else wait_vm0();
    barrier_raw();   // all waves' tile-ks loads landed in S
    const bf16* As = S; const bf16* Bs = S + 128*32;
    short8 af[4], bv[6];
#pragma unroll
    for (int i = 0; i < 4; ++i)
      af[i] = *(const short8*)(As + (wr + i*16 + ln) * 32 + swz);
#pragma unroll
    for (int j = 0; j < 6; ++j)
      bv[j] = *(const short8*)(Bs + (wc + j*16 + ln) * 32 + swz);
#pragma unroll
    for (int i = 0; i < 4; ++i)
#pragma unroll
      for (int j = 0; j < 6; ++j)
        acc[i][j] = __builtin_amdgcn_mfma_f32_16x16x32_bf16(af[i], bv[j], acc[i][j], 0, 0, 0);
    barrier_raw();   // readers of S done before next iter writes S
  }
  const int hbase = jb * 64 + (wave & 1) * 32;
#pragma unroll
  for (int jg = 0; jg < 2; ++jg) {
    const int jj = hbase + jg * 16 + ln;
    const int jc = (jj < 1000) ? jj : 999;
    const float bI = bf2f(bvec[dir * 4000 + jc]);
    const float bG = bf2f(bvec[dir * 4000 + 2000 + jc]);
    const float bO = bf2f(bvec[dir * 4000 + 3000 + jc]);
    const int col = dir * 1000 + jj;
    const bool sv = (jj < 1000);
    const bool sz = (!sv) && (dir == 1) && (col < ldc);
    if (!sv && !sz) continue;
#pragma unroll
    for (int i = 0; i < 4; ++i)
#pragma unroll
      for (int r = 0; r < 4; ++r) {
        long m = m0 + wr + i * 16 + lq * 4 + r;
        float h = 0.f;
        if (sv) {
          float gi = acc[i][jg*3+0][r] + bI;
          float gg = acc[i][jg*3+1][r] + bG;
          float go = acc[i][jg*3+2][r] + bO;
          float cc = sigm(gi) * tanhfast(gg);
          h = sigm(go) * tanhfast(cc);
          if (combine) h = 0.5f * (h + bf2f(other[m * ldo + col]));
        }
        Hout[m * ldc + col] = f2bf(h);
      }
  }
}

// mean over 24 neighbors of h: X [512*24, 2016] bf16 -> Y [512, 2016] bf16
__global__ __launch_bounds__(256) void meanh(const bf16* __restrict__ X, bf16* __restrict__ Y)
{
  long idx = (long)blockIdx.x * 256 + threadIdx.x;
  if (idx >= 512l * 2016) return;
  long b = idx / 2016, e = idx % 2016;
  const bf16* p = X + b * 24 * 2016 + e;
  float s = 0.f;
#pragma unroll
  for (int n = 0; n < 24; ++n) s += bf2f(p[(long)n * 2016]);
  Y[idx] = f2bf(s * (1.f / 24.f));
}

// attention over {c, u_agg, p_agg} + weighted mix -> out [512,2000] fp32
__global__ __launch_bounds__(256) void attn_mix(
    const bf16* __restrict__ Cm, const float* __restrict__ U,
    const float* __restrict__ P, const float* __restrict__ att,
    float* __restrict__ out, int ldcm)
{
  const int b = blockIdx.x, tid = threadIdx.x;
  __shared__ float red[4][4];
  __shared__ float wsh[3];
  float s0 = 0, s1 = 0, s2 = 0, s3 = 0;
  const long baseC = (long)b * ldcm;
  const long base  = (long)b * 2000;
  for (int e = tid; e < 2000; e += 256) {
    float cv = bf2f(Cm[baseC + e]);
    float al = att[e];
    float ah = att[2000 + e];
    s0 += cv * al; s1 += cv * ah;
    s2 += U[base + e] * ah; s3 += P[base + e] * ah;
  }
#pragma unroll
  for (int o = 32; o; o >>= 1) {
    s0 += __shfl_down(s0, o); s1 += __shfl_down(s1, o);
    s2 += __shfl_down(s2, o); s3 += __shfl_down(s3, o);
  }
  if ((tid & 63) == 0) {
    int w = tid >> 6;
    red[w][0] = s0; red[w][1] = s1; red[w][2] = s2; red[w][3] = s3;
  }
  __syncthreads();
  if (tid == 0) {
    float a0 = 0, a1 = 0, a2 = 0, a3 = 0;
    for (int w = 0; w < 4; ++w) { a0 += red[w][0]; a1 += red[w][1]; a2 += red[w][2]; a3 += red[w][3]; }
    float t0 = a0 + a1, t1 = a0 + a2, t2 = a0 + a3;
    t0 = t0 > 0 ? t0 : 0.01f * t0;
    t1 = t1 > 0 ? t1 : 0.01f * t1;
    t2 = t2 > 0 ? t2 : 0.01f * t2;
    float mx = fmaxf(t0, fmaxf(t1, t2));
    float e0 = __expf(t0 - mx), e1 = __expf(t1 - mx), e2 = __expf(t2 - mx);
    float inv = 1.f / (e0 + e1 + e2);
    wsh[0] = e0 * inv; wsh[1] = e1 * inv; wsh[2] = e2 * inv;
  }
  __syncthreads();
  float w0 = wsh[0], w1 = wsh[1], w2 = wsh[2];
  for (int e = tid; e < 2000; e += 256)
    out[base + e] = w0 * bf2f(Cm[baseC + e]) + w1 * U[base + e] + w2 * P[base + e];
}

extern "C" void kernel_launch(void* const* d_in, const int* in_sizes, int n_in,
                              void* d_out, int out_size, void* d_ws, size_t ws_size,
                              hipStream_t stream)
{
  const float* c_text  = (const float*)d_in[0];
  const float* c_image = (const float*)d_in[1];
  const float* p_text  = (const float*)d_in[2];
  const float* p_image = (const float*)d_in[3];
  const float* u_text  = (const float*)d_in[4];
  const float* u_other = (const float*)d_in[5];
  const float* p_att   = (const float*)d_in[30];
  float* out = (float*)d_out;

  char* ws = (char*)d_ws;
  size_t off = 0;
  auto alloc = [&](size_t bytes) -> char* {
    char* p = ws + off; off += (bytes + 255) & ~(size_t)255; return p;
  };
  bf16* ARENA = (bf16*)alloc(32282496ull * 2);
  bf16* BIG1  = (bf16*)alloc(12800ull * 2016 * 2);   // lstm_t h / agg h
  bf16* BIG2  = (bf16*)alloc(12800ull * 2016 * 2);   // combined birnn out
  bf16* X1    = (bf16*)alloc(12800ull * 512 * 2);
  bf16* X2    = (bf16*)alloc(12800ull * 512 * 2);
  bf16* Yu    = (bf16*)alloc(512ull * 2016 * 2);     // user agg mean-h
  bf16* Yp    = (bf16*)alloc(512ull * 2016 * 2);     // post agg mean-h
  float* UA   = (float*)alloc(512ull * 2000 * 4);
  float* PA   = (float*)alloc(512ull * 2000 * 4);
  (void)ws_size; (void)in_sizes; (void)n_in; (void)out_size;

  const bf16* aW_lt = ARENA + 0;        const bf16* ab_lt = ARENA + 393216;
  const bf16* aW_li = ARENA + 393728;   const bf16* ab_li = ARENA + 1442304;
  const bf16* aW_lo = ARENA + 1442816;  const bf16* ab_lo = ARENA + 1704960;
  const bf16* alt_W = ARENA + 1705472;  const bf16* alt_b = ARENA + 5801472;
  const bf16* ali_W = ARENA + 5809472;  const bf16* ali_b = ARENA + 9905472;
  const bf16* alo_W = ARENA + 9913472;  const bf16* alo_b = ARENA + 14009472;
  const bf16* aua_lin_W  = ARENA + 14017472; const bf16* aua_lin_b  = ARENA + 15041472;
  const bf16* aua_lstm_W = ARENA + 15041984; const bf16* aua_lstm_b = ARENA + 19137984;
  const bf16* aua_out_W  = ARENA + 19145984; const bf16* aua_out_b  = ARENA + 23145984;
  const bf16* apa_lin_W  = ARENA + 23147984; const bf16* apa_lin_b  = ARENA + 24171984;
  const bf16* apa_lstm_W = ARENA + 24172496; const bf16* apa_lstm_b = ARENA + 28268496;
  const bf16* apa_out_W  = ARENA + 28276496; const bf16* apa_out_b  = ARENA + 32276496;

  CvtPtrs cp;
  for (int i = 0; i < 25; ++i) cp.p[i] = (const float*)d_in[6 + i];
  cvt_all<<<dim3(31527), dim3(256), 0, stream>>>(cp, ARENA);

  dim3 blk(256);
  const int NOSPLIT = 1 << 30;

  // ---- user path, M=12288
  gemm_linA32<<<dim3(96,4), blk, 0, stream>>>(u_text,  u_text,  NOSPLIT, aW_lt, ab_lt, X1, 12288, 512, 768, 768, 768, 512);
  gemm_linA32<<<dim3(96,4), blk, 0, stream>>>(u_other, u_other, NOSPLIT, aW_lo, ab_lo, X2, 12288, 512, 512, 512, 512, 512);
  gemm_lstm<<<dim3(96,32), blk, 0, stream>>>(X1, alt_W, alt_b, nullptr, BIG1, 2016, 2016, 0);
  gemm_lstm<<<dim3(96,32), blk, 0, stream>>>(X2, alo_W, alo_b, BIG1,    BIG2, 2016, 2016, 1);
  gemm_lin<<<dim3(96,4), blk, 0, stream>>>(BIG2, aua_lin_W, aua_lin_b, X1, 12288, 512, 2000, 2016, 2000, 512);
  gemm_lstm<<<dim3(96,32), blk, 0, stream>>>(X1, aua_lstm_W, aua_lstm_b, nullptr, BIG1, 2016, 2016, 0);
  meanh<<<dim3(4032), blk, 0, stream>>>(BIG1, Yu);

  // ---- post + center path, M=12800 (rows 12288..12799 = center)
  gemm_linA32<<<dim3(100,4), blk, 0, stream>>>(p_text,  c_text,  96, aW_lt, ab_lt, X1, 12800, 512, 768,  768,  768,  512);
  gemm_linA32<<<dim3(100,4), blk, 0, stream>>>(p_image, c_image, 96, aW_li, ab_li, X2, 12800, 512, 2048, 2048, 2048, 512);
  gemm_lstm<<<dim3(100,32), blk, 0, stream>>>(X1, alt_W, alt_b, nullptr, BIG1, 2016, 2016, 0);
  gemm_lstm<<<dim3(100,32), blk, 0, stream>>>(X2, ali_W, ali_b, BIG1,    BIG2, 2016, 2016, 1);
  // agg uses only the 12288 post-neighbor rows of BIG2
  gemm_lin<<<dim3(96,4), blk, 0, stream>>>(BIG2, apa_lin_W, apa_lin_b, X1, 12288, 512, 2000, 2016, 2000, 512);
  gemm_lstm<<<dim3(96,32), blk, 0, stream>>>(X1, apa_lstm_W, apa_lstm_b, nullptr, BIG1, 2016, 2016, 0);
  meanh<<<dim3(4032), blk, 0, stream>>>(BIG1, Yp);

  // ---- merged agg out-GEMMs (M=512 each, one launch), then attention
  gemm_out_f32<<<dim3(8,16), blk, 0, stream>>>(Yu, Yp, aua_out_W, apa_out_W,
                                               aua_out_b, apa_out_b, UA, PA);
  attn_mix<<<dim3(512), blk, 0, stream>>>(BIG2 + 12288l * 2016, UA, PA, p_att, out, 2016);
}

// Round 13
// 1475.633 us; speedup vs baseline: 1.0371x; 1.0371x over previous
//
#include <hip/hip_runtime.h>
#include <hip/hip_bf16.h>

// Round 16: R14 (verified 1490.1us: 128x32 lstm tile, counted vmcnt(4/3))
// + the R15-verified conflict-free LDS swizzle ONLY (SQ_LDS_BANK_CONFLICT
// 1.147e7 -> 0.0 on hardware). R15's wide tile reverted (occupancy 42->21%
// regression). Staging: pre-swizzled global chunk, linear LDS dest; reads:
// per-lane-const swz. Bit-identical numerics.

typedef __hip_bfloat16 bf16;
typedef __attribute__((ext_vector_type(8))) short short8;
typedef __attribute__((ext_vector_type(4))) float f32x4;

__device__ __forceinline__ float bf2f(bf16 x){ return __bfloat162float(x); }
__device__ __forceinline__ bf16  f2bf(float x){ return __float2bfloat16(x); }

__device__ __forceinline__ void gld16(const bf16* g, bf16* l){
  __builtin_amdgcn_global_load_lds(
      (const __attribute__((address_space(1))) void*)g,
      (__attribute__((address_space(3))) void*)l, 16, 0, 0);
}

__device__ __forceinline__ void barrier_raw(){ asm volatile("s_barrier" ::: "memory"); }
__device__ __forceinline__ void wait_vm0(){ asm volatile("s_waitcnt vmcnt(0)" ::: "memory"); }
__device__ __forceinline__ void wait_vm3(){ asm volatile("s_waitcnt vmcnt(3)" ::: "memory"); }
__device__ __forceinline__ void wait_vm4(){ asm volatile("s_waitcnt vmcnt(4)" ::: "memory"); }

__device__ __forceinline__ float sigm(float x){ return 1.0f/(1.0f + __expf(-x)); }
__device__ __forceinline__ float tanhfast(float x){
  x = fminf(fmaxf(x, -15.f), 15.f);
  float e = __expf(2.f*x);
  return (e-1.f)/(e+1.f);
}

// ---------------------------------------------------------------------------
// Batched fp32 -> bf16 weight conversion into arena.
// ---------------------------------------------------------------------------
struct CvtPtrs { const float* p[25]; };
__constant__ long CVT_CUM[26] = {0, 98304, 98432, 360576, 360704, 426240,
  426368, 1450368, 1452368, 2476368, 2478368, 3502368, 3504368, 3760368,
  3760496, 4784496, 4786496, 5786496, 5786996, 6042996, 6043124, 7067124,
  7069124, 8069124, 8069624, 8070624};

__global__ __launch_bounds__(256) void cvt_all(CvtPtrs P, bf16* __restrict__ arena)
{
  long g = (long)blockIdx.x * 256 + threadIdx.x;
  if (g >= 8070624l) return;
  int lo = 0, hi = 24;
  while (lo < hi) { int mid = (lo + hi + 1) >> 1; if (g >= CVT_CUM[mid]) lo = mid; else hi = mid - 1; }
  long rel = (g - CVT_CUM[lo]) * 4;
  float4 v = *(const float4*)(P.p[lo] + rel);
  union { bf16 h[4]; uint2 u; } t;
  t.h[0]=f2bf(v.x); t.h[1]=f2bf(v.y); t.h[2]=f2bf(v.z); t.h[3]=f2bf(v.w);
  *(uint2*)(arena + CVT_CUM[lo]*4 + rel) = t.u;
}

// ---------------------------------------------------------------------------
// bt-GEMM, fp32 A / bf16 B: C = A @ Bt^T + bias (bf16 out). 128x128, BK=32.
// 2-phase double-buffered. Segmented A (splitx). K%32==0, gridDim.x*128==M.
// ---------------------------------------------------------------------------
__global__ __launch_bounds__(256) void gemm_linA32(
    const float* __restrict__ A, const float* __restrict__ A2, int splitx,
    const bf16* __restrict__ Bt, const bf16* __restrict__ bias,
    bf16* __restrict__ C, int M, int N, int K, int lda, int ldb, int ldc)
{
  __shared__ bf16 sm[2][(128+128)*32];
  const int tid  = threadIdx.x;
  const int wave = tid >> 6, lane = tid & 63;
  const int wr = (wave >> 1) * 64, wc = (wave & 1) * 64;
  const int ln = lane & 15, lq = lane >> 4;
  const long m0 = (long)blockIdx.x * 128;           // global output row base
  const int  n0 = blockIdx.y * 128;

  const float* Abase; long mrow;
  if ((int)blockIdx.x < splitx) { Abase = A;  mrow = m0; }
  else { Abase = A2; mrow = (long)((int)blockIdx.x - splitx) * 128; }

  const int arow = tid >> 1, ahalf = (tid & 1) * 16;
  const float* pA = Abase + (mrow + arow) * (long)lda + ahalf;
  const int sAoff = arow * 32 + ahalf;              // elements into As
  const int ch = (tid & 3) * 8;
  int colA = n0 + (tid >> 2);       colA = (colA < N) ? colA : (N - 1);
  int colB = n0 + (tid >> 2) + 64;  colB = (colB < N) ? colB : (N - 1);
  const bf16* pB0 = Bt + (long)colA * ldb + ch;
  const bf16* pB1 = Bt + (long)colB * ldb + ch;
  const int sB0 = 128*32 + tid * 8, sB1 = 128*32 + (tid + 256) * 8;

  auto cvtA = [&](bf16* dst, float4 v0, float4 v1, float4 v2, float4 v3){
    union { bf16 h[16]; short8 q[2]; } u;
    u.h[0]=f2bf(v0.x); u.h[1]=f2bf(v0.y); u.h[2]=f2bf(v0.z); u.h[3]=f2bf(v0.w);
    u.h[4]=f2bf(v1.x); u.h[5]=f2bf(v1.y); u.h[6]=f2bf(v1.z); u.h[7]=f2bf(v1.w);
    u.h[8]=f2bf(v2.x); u.h[9]=f2bf(v2.y); u.h[10]=f2bf(v2.z); u.h[11]=f2bf(v2.w);
    u.h[12]=f2bf(v3.x); u.h[13]=f2bf(v3.y); u.h[14]=f2bf(v3.z); u.h[15]=f2bf(v3.w);
    *(short8*)(dst)     = u.q[0];
    *(short8*)(dst + 8) = u.q[1];
  };

  const int ksteps = K >> 5;
  { // prologue: stage tile 0 into buffer 0
    float4 v0 = *(const float4*)(pA);
    float4 v1 = *(const float4*)(pA + 4);
    float4 v2 = *(const float4*)(pA + 8);
    float4 v3 = *(const float4*)(pA + 12);
    cvtA(sm[0] + sAoff, v0, v1, v2, v3);
    gld16(pB0, sm[0] + sB0);
    gld16(pB1, sm[0] + sB1);
    pA += 32; pB0 += 32; pB1 += 32;
  }
  __syncthreads();

  f32x4 acc[4][4] = {};
  for (int ks = 0; ks < ksteps; ++ks) {
    const bf16* S = sm[ks & 1];
    bf16* Sn = sm[(ks + 1) & 1];
    const bool stage = (ks + 1 < ksteps);
    float4 v0, v1, v2, v3;
    if (stage) {
      v0 = *(const float4*)(pA);
      v1 = *(const float4*)(pA + 4);
      v2 = *(const float4*)(pA + 8);
      v3 = *(const float4*)(pA + 12);
      gld16(pB0, Sn + sB0);
      gld16(pB1, Sn + sB1);
      pA += 32; pB0 += 32; pB1 += 32;
    }
    const bf16* As = S; const bf16* Bs = S + 128*32;
    short8 af[4], bv[4];
#pragma unroll
    for (int i = 0; i < 4; ++i)
      af[i] = *(const short8*)(As + (wr + i*16 + ln) * 32 + lq * 8);
#pragma unroll
    for (int j = 0; j < 4; ++j)
      bv[j] = *(const short8*)(Bs + (wc + j*16 + ln) * 32 + lq * 8);
#pragma unroll
    for (int i = 0; i < 4; ++i)
#pragma unroll
      for (int j = 0; j < 4; ++j)
        acc[i][j] = __builtin_amdgcn_mfma_f32_16x16x32_bf16(af[i], bv[j], acc[i][j], 0, 0, 0);
    if (stage) cvtA(Sn + sAoff, v0, v1, v2, v3);
    __syncthreads();
  }
#pragma unroll
  for (int j = 0; j < 4; ++j) {
    int n = n0 + wc + j * 16 + ln;
    if (n < N) {
      float bvv = bf2f(bias[n]);
#pragma unroll
      for (int i = 0; i < 4; ++i)
#pragma unroll
        for (int r = 0; r < 4; ++r) {
          long m = m0 + wr + i * 16 + lq * 4 + r;
          C[m * ldc + n] = f2bf(acc[i][j][r] + bvv);
        }
    } else if (n < ldc) {
#pragma unroll
      for (int i = 0; i < 4; ++i)
#pragma unroll
        for (int r = 0; r < 4; ++r) {
          long m = m0 + wr + i * 16 + lq * 4 + r;
          C[m * ldc + n] = f2bf(0.f);
        }
    }
  }
}

// ---------------------------------------------------------------------------
// bt-GEMM, bf16 A / bf16 B, bf16 out. 2-phase double-buffered.
// A zero-padded over [K, 32*ceil(K/32)). B overreads <=16 elems hit A-zeros.
// ---------------------------------------------------------------------------
__global__ __launch_bounds__(256) void gemm_lin(
    const bf16* __restrict__ A, const bf16* __restrict__ Bt,
    const bf16* __restrict__ bias, bf16* __restrict__ C,
    int M, int N, int K, int lda, int ldb, int ldc)
{
  __shared__ bf16 sm[2][(128+128)*32];
  const int tid  = threadIdx.x;
  const int wave = tid >> 6, lane = tid & 63;
  const int wr = (wave >> 1) * 64, wc = (wave & 1) * 64;
  const int ln = lane & 15, lq = lane >> 4;
  const long m0 = (long)blockIdx.x * 128;
  const int  n0 = blockIdx.y * 128;

  const int ch = (tid & 3) * 8;
  const bf16* pA0 = A + (m0 + (tid >> 2)) * (long)lda + ch;
  const bf16* pA1 = A + (m0 + (tid >> 2) + 64) * (long)lda + ch;
  int colA = n0 + (tid >> 2);       colA = (colA < N) ? colA : (N - 1);
  int colB = n0 + (tid >> 2) + 64;  colB = (colB < N) ? colB : (N - 1);
  const bf16* pB0 = Bt + (long)colA * ldb + ch;
  const bf16* pB1 = Bt + (long)colB * ldb + ch;
  const int sA0 = tid * 8, sA1 = (tid + 256) * 8;
  const int sB0 = 128*32 + tid * 8, sB1 = 128*32 + (tid + 256) * 8;

  const int ksteps = (K + 31) >> 5;
  {
    gld16(pA0, sm[0] + sA0); gld16(pA1, sm[0] + sA1);
    gld16(pB0, sm[0] + sB0); gld16(pB1, sm[0] + sB1);
    pA0 += 32; pA1 += 32; pB0 += 32; pB1 += 32;
  }
  __syncthreads();

  f32x4 acc[4][4] = {};
  for (int ks = 0; ks < ksteps; ++ks) {
    const bf16* S = sm[ks & 1];
    bf16* Sn = sm[(ks + 1) & 1];
    if (ks + 1 < ksteps) {
      gld16(pA0, Sn + sA0); gld16(pA1, Sn + sA1);
      gld16(pB0, Sn + sB0); gld16(pB1, Sn + sB1);
      pA0 += 32; pA1 += 32; pB0 += 32; pB1 += 32;
    }
    const bf16* As = S; const bf16* Bs = S + 128*32;
    short8 af[4], bv[4];
#pragma unroll
    for (int i = 0; i < 4; ++i)
      af[i] = *(const short8*)(As + (wr + i*16 + ln) * 32 + lq * 8);
#pragma unroll
    for (int j = 0; j < 4; ++j)
      bv[j] = *(const short8*)(Bs + (wc + j*16 + ln) * 32 + lq * 8);
#pragma unroll
    for (int i = 0; i < 4; ++i)
#pragma unroll
      for (int j = 0; j < 4; ++j)
        acc[i][j] = __builtin_amdgcn_mfma_f32_16x16x32_bf16(af[i], bv[j], acc[i][j], 0, 0, 0);
    __syncthreads();
  }
#pragma unroll
  for (int j = 0; j < 4; ++j) {
    int n = n0 + wc + j * 16 + ln;
    if (n < N) {
      float bvv = bf2f(bias[n]);
#pragma unroll
      for (int i = 0; i < 4; ++i)
#pragma unroll
        for (int r = 0; r < 4; ++r) {
          long m = m0 + wr + i * 16 + lq * 4 + r;
          C[m * ldc + n] = f2bf(acc[i][j][r] + bvv);
        }
    } else if (n < ldc) {
#pragma unroll
      for (int i = 0; i < 4; ++i)
#pragma unroll
        for (int r = 0; r < 4; ++r) {
          long m = m0 + wr + i * 16 + lq * 4 + r;
          C[m * ldc + n] = f2bf(0.f);
        }
    }
  }
}

// ---------------------------------------------------------------------------
// Merged agg out-GEMM, fp32 out, 2-phase double-buffered. Two 512x2000x2000
// problems: grid (8,16); blocks 0..3 -> seg0, 4..7 -> seg1.
// ---------------------------------------------------------------------------
__global__ __launch_bounds__(256) void gemm_out_f32(
    const bf16* __restrict__ A0, const bf16* __restrict__ A1,
    const bf16* __restrict__ B0, const bf16* __restrict__ B1,
    const bf16* __restrict__ b0, const bf16* __restrict__ b1,
    float* __restrict__ C0, float* __restrict__ C1)
{
  __shared__ bf16 sm[2][(128+128)*32];
  const int tid  = threadIdx.x;
  const int wave = tid >> 6, lane = tid & 63;
  const int wr = (wave >> 1) * 64, wc = (wave & 1) * 64;
  const int ln = lane & 15, lq = lane >> 4;
  const int seg = blockIdx.x >> 2;
  const long m0 = (long)(blockIdx.x & 3) * 128;
  const int  n0 = blockIdx.y * 128;
  const int N = 2000, lda = 2016, ldb = 2000, ldc = 2000;

  const bf16* A    = seg ? A1 : A0;
  const bf16* Bt   = seg ? B1 : B0;
  const bf16* bias = seg ? b1 : b0;
  float*      C    = seg ? C1 : C0;

  const int ch = (tid & 3) * 8;
  const bf16* pA0 = A + (m0 + (tid >> 2)) * (long)lda + ch;
  const bf16* pA1 = A + (m0 + (tid >> 2) + 64) * (long)lda + ch;
  int colA = n0 + (tid >> 2);       colA = (colA < N) ? colA : (N - 1);
  int colB = n0 + (tid >> 2) + 64;  colB = (colB < N) ? colB : (N - 1);
  const bf16* pB0 = Bt + (long)colA * ldb + ch;
  const bf16* pB1 = Bt + (long)colB * ldb + ch;
  const int sA0 = tid * 8, sA1 = (tid + 256) * 8;
  const int sB0 = 128*32 + tid * 8, sB1 = 128*32 + (tid + 256) * 8;

  {
    gld16(pA0, sm[0] + sA0); gld16(pA1, sm[0] + sA1);
    gld16(pB0, sm[0] + sB0); gld16(pB1, sm[0] + sB1);
    pA0 += 32; pA1 += 32; pB0 += 32; pB1 += 32;
  }
  __syncthreads();

  f32x4 acc[4][4] = {};
  for (int ks = 0; ks < 63; ++ks) {          // K = 2000 -> 63 steps of 32
    const bf16* S = sm[ks & 1];
    bf16* Sn = sm[(ks + 1) & 1];
    if (ks + 1 < 63) {
      gld16(pA0, Sn + sA0); gld16(pA1, Sn + sA1);
      gld16(pB0, Sn + sB0); gld16(pB1, Sn + sB1);
      pA0 += 32; pA1 += 32; pB0 += 32; pB1 += 32;
    }
    const bf16* As = S; const bf16* Bs = S + 128*32;
    short8 af[4], bv[4];
#pragma unroll
    for (int i = 0; i < 4; ++i)
      af[i] = *(const short8*)(As + (wr + i*16 + ln) * 32 + lq * 8);
#pragma unroll
    for (int j = 0; j < 4; ++j)
      bv[j] = *(const short8*)(Bs + (wc + j*16 + ln) * 32 + lq * 8);
#pragma unroll
    for (int i = 0; i < 4; ++i)
#pragma unroll
      for (int j = 0; j < 4; ++j)
        acc[i][j] = __builtin_amdgcn_mfma_f32_16x16x32_bf16(af[i], bv[j], acc[i][j], 0, 0, 0);
    __syncthreads();
  }
#pragma unroll
  for (int j = 0; j < 4; ++j) {
    int n = n0 + wc + j * 16 + ln;
    if (n < N) {
      float bvv = bf2f(bias[n]);
#pragma unroll
      for (int i = 0; i < 4; ++i)
#pragma unroll
        for (int r = 0; r < 4; ++r) {
          long m = m0 + wr + i * 16 + lq * 4 + r;
          C[m * ldc + n] = acc[i][j][r] + bvv;
        }
    }
  }
}

// ---------------------------------------------------------------------------
// Fused single-step BiLSTM gate GEMM + activation (f-gate dead; h0=c0=0).
// 128x32h tile (R14 geometry, 42% occupancy) + counted vmcnt(4/3) + raw
// s_barrier (R14 template) + conflict-free LDS chunk swizzle (R15-verified:
// bank conflicts 1.147e7 -> 0). Staging reads pre-swizzled GLOBAL chunk
// ch=((tid&3)^((tid>>3)&3))*8 into linear LDS slot; compute reads add
// per-lane-const swz=(lq^((ln>>1)&3))*8. Bit-identical numerics.
// ---------------------------------------------------------------------------
__global__ __launch_bounds__(256) void gemm_lstm(
    const bf16* __restrict__ A, const bf16* __restrict__ W,
    const bf16* __restrict__ bvec, const bf16* __restrict__ other,
    bf16* __restrict__ Hout, int ldo, int ldc, int combine)
{
  __shared__ bf16 sm[2][(128+96)*32];
  const int tid  = threadIdx.x;
  const int wave = tid >> 6, lane = tid & 63;
  const int wr = (wave >> 1) * 64, wc = (wave & 1) * 48;
  const int ln = lane & 15, lq = lane >> 4;
  const long m0 = (long)blockIdx.x * 128;
  const int dir = blockIdx.y >> 5, jb = blockIdx.y & 31;

  // pre-swizzled chunk: LDS slot (row=s>>2, pos=s&3) receives global chunk
  // pos ^ ((row>>1)&3). All slots of thread tid (rows differ by 64 ≡ 0 mod 4)
  // share (row>>1)&3 == (tid>>3)&3.
  const int ch = ((tid & 3) ^ ((tid >> 3) & 3)) * 8;
  const bf16* pA0 = A + (m0 + (tid >> 2)) * 512 + ch;
  const bf16* pA1 = A + (m0 + (tid >> 2) + 64) * 512 + ch;
  auto brow = [&](int t) -> long {
    int tc = t >> 2;
    int grp = tc / 48, wi = tc % 48, cf = wi >> 4;
    int jj = jb * 32 + grp * 16 + (wi & 15);
    jj = (jj < 1000) ? jj : 999;
    return (long)(dir * 4000 + cf * 1000 + (cf ? 1000 : 0) + jj);
  };
  const bf16* pB0 = W + brow(tid) * 512 + ch;
  const bf16* pB1 = W + brow(tid + 256) * 512 + ch;   // used only if tid<128
  const int sA0 = tid * 8, sA1 = (tid + 256) * 8;
  const int sB0 = 128*32 + tid * 8, sB1 = 128*32 + (tid + 256) * 8;
  const bool doB1 = (tid < 128);
  // read-side swizzle: rows are 16k+ln -> (row>>1)&3 == (ln>>1)&3
  const int swz = (lq ^ ((ln >> 1) & 3)) * 8;

  { // prologue: stage tile 0 (stays in flight; loop's vmcnt+barrier syncs)
    gld16(pA0, sm[0] + sA0); gld16(pA1, sm[0] + sA1);
    gld16(pB0, sm[0] + sB0);
    if (doB1) gld16(pB1, sm[0] + sB1);
    pA0 += 32; pA1 += 32; pB0 += 32; pB1 += 32;
  }

  f32x4 acc[4][3] = {};
  for (int ks = 0; ks < 16; ++ks) {          // K = 512
    const bf16* S = sm[ks & 1];
    bf16* Sn = sm[(ks + 1) & 1];
    const bool stage = (ks + 1 < 16);
    if (stage) {
      gld16(pA0, Sn + sA0); gld16(pA1, Sn + sA1);
      gld16(pB0, Sn + sB0);
      if (doB1) gld16(pB1, Sn + sB1);
      pA0 += 32; pA1 += 32; pB0 += 32; pB1 += 32;
    }
    // wait only for tile-ks loads; tile-(ks+1) loads stay in flight
    if (!stage)      wait_vm0();
    else if (doB1)   wait_vm4();
    else             wait_vm3();
    barrier_raw();   // all waves' tile-ks loads landed in S
    const bf16* As = S; const bf16* Bs = S + 128*32;
    short8 af[4], bv[3];
#pragma unroll
    for (int i = 0; i < 4; ++i)
      af[i] = *(const short8*)(As + (wr + i*16 + ln) * 32 + swz);
#pragma unroll
    for (int j = 0; j < 3; ++j)
      bv[j] = *(const short8*)(Bs + (wc + j*16 + ln) * 32 + swz);
#pragma unroll
    for (int i = 0; i < 4; ++i)
#pragma unroll
      for (int j = 0; j < 3; ++j)
        acc[i][j] = __builtin_amdgcn_mfma_f32_16x16x32_bf16(af[i], bv[j], acc[i][j], 0, 0, 0);
    barrier_raw();   // readers of S done before next iter writes S
  }
  const int jj  = jb * 32 + (wave & 1) * 16 + ln;
  const int jc  = (jj < 1000) ? jj : 999;
  const float bI = bf2f(bvec[dir * 4000 + jc]);
  const float bG = bf2f(bvec[dir * 4000 + 2000 + jc]);
  const float bO = bf2f(bvec[dir * 4000 + 3000 + jc]);
  const int col = dir * 1000 + jj;
  const bool sv = (jj < 1000);
  const bool sz = (!sv) && (dir == 1) && (col < ldc);
  if (!sv && !sz) return;
#pragma unroll
  for (int i = 0; i < 4; ++i)
#pragma unroll
    for (int r = 0; r < 4; ++r) {
      long m = m0 + wr + i * 16 + lq * 4 + r;
      float h = 0.f;
      if (sv) {
        float gi = acc[i][0][r] + bI;
        float gg = acc[i][1][r] + bG;
        float go = acc[i][2][r] + bO;
        float cc = sigm(gi) * tanhfast(gg);
        h = sigm(go) * tanhfast(cc);
        if (combine) h = 0.5f * (h + bf2f(other[m * ldo + col]));
      }
      Hout[m * ldc + col] = f2bf(h);
    }
}

// mean over 24 neighbors of h: X [512*24, 2016] bf16 -> Y [512, 2016] bf16
__global__ __launch_bounds__(256) void meanh(const bf16* __restrict__ X, bf16* __restrict__ Y)
{
  long idx = (long)blockIdx.x * 256 + threadIdx.x;
  if (idx >= 512l * 2016) return;
  long b = idx / 2016, e = idx % 2016;
  const bf16* p = X + b * 24 * 2016 + e;
  float s = 0.f;
#pragma unroll
  for (int n = 0; n < 24; ++n) s += bf2f(p[(long)n * 2016]);
  Y[idx] = f2bf(s * (1.f / 24.f));
}

// attention over {c, u_agg, p_agg} + weighted mix -> out [512,2000] fp32
__global__ __launch_bounds__(256) void attn_mix(
    const bf16* __restrict__ Cm, const float* __restrict__ U,
    const float* __restrict__ P, const float* __restrict__ att,
    float* __restrict__ out, int ldcm)
{
  const int b = blockIdx.x, tid = threadIdx.x;
  __shared__ float red[4][4];
  __shared__ float wsh[3];
  float s0 = 0, s1 = 0, s2 = 0, s3 = 0;
  const long baseC = (long)b * ldcm;
  const long base  = (long)b * 2000;
  for (int e = tid; e < 2000; e += 256) {
    float cv = bf2f(Cm[baseC + e]);
    float al = att[e];
    float ah = att[2000 + e];
    s0 += cv * al; s1 += cv * ah;
    s2 += U[base + e] * ah; s3 += P[base + e] * ah;
  }
#pragma unroll
  for (int o = 32; o; o >>= 1) {
    s0 += __shfl_down(s0, o); s1 += __shfl_down(s1, o);
    s2 += __shfl_down(s2, o); s3 += __shfl_down(s3, o);
  }
  if ((tid & 63) == 0) {
    int w = tid >> 6;
    red[w][0] = s0; red[w][1] = s1; red[w][2] = s2; red[w][3] = s3;
  }
  __syncthreads();
  if (tid == 0) {
    float a0 = 0, a1 = 0, a2 = 0, a3 = 0;
    for (int w = 0; w < 4; ++w) { a0 += red[w][0]; a1 += red[w][1]; a2 += red[w][2]; a3 += red[w][3]; }
    float t0 = a0 + a1, t1 = a0 + a2, t2 = a0 + a3;
    t0 = t0 > 0 ? t0 : 0.01f * t0;
    t1 = t1 > 0 ? t1 : 0.01f * t1;
    t2 = t2 > 0 ? t2 : 0.01f * t2;
    float mx = fmaxf(t0, fmaxf(t1, t2));
    float e0 = __expf(t0 - mx), e1 = __expf(t1 - mx), e2 = __expf(t2 - mx);
    float inv = 1.f / (e0 + e1 + e2);
    wsh[0] = e0 * inv; wsh[1] = e1 * inv; wsh[2] = e2 * inv;
  }
  __syncthreads();
  float w0 = wsh[0], w1 = wsh[1], w2 = wsh[2];
  for (int e = tid; e < 2000; e += 256)
    out[base + e] = w0 * bf2f(Cm[baseC + e]) + w1 * U[base + e] + w2 * P[base + e];
}

extern "C" void kernel_launch(void* const* d_in, const int* in_sizes, int n_in,
                              void* d_out, int out_size, void* d_ws, size_t ws_size,
                              hipStream_t stream)
{
  const float* c_text  = (const float*)d_in[0];
  const float* c_image = (const float*)d_in[1];
  const float* p_text  = (const float*)d_in[2];
  const float* p_image = (const float*)d_in[3];
  const float* u_text  = (const float*)d_in[4];
  const float* u_other = (const float*)d_in[5];
  const float* p_att   = (const float*)d_in[30];
  float* out = (float*)d_out;

  char* ws = (char*)d_ws;
  size_t off = 0;
  auto alloc = [&](size_t bytes) -> char* {
    char* p = ws + off; off += (bytes + 255) & ~(size_t)255; return p;
  };
  bf16* ARENA = (bf16*)alloc(32282496ull * 2);
  bf16* BIG1  = (bf16*)alloc(12800ull * 2016 * 2);   // lstm_t h / agg h
  bf16* BIG2  = (bf16*)alloc(12800ull * 2016 * 2);   // combined birnn out
  bf16* X1    = (bf16*)alloc(12800ull * 512 * 2);
  bf16* X2    = (bf16*)alloc(12800ull * 512 * 2);
  bf16* Yu    = (bf16*)alloc(512ull * 2016 * 2);     // user agg mean-h
  bf16* Yp    = (bf16*)alloc(512ull * 2016 * 2);     // post agg mean-h
  float* UA   = (float*)alloc(512ull * 2000 * 4);
  float* PA   = (float*)alloc(512ull * 2000 * 4);
  (void)ws_size; (void)in_sizes; (void)n_in; (void)out_size;

  const bf16* aW_lt = ARENA + 0;        const bf16* ab_lt = ARENA + 393216;
  const bf16* aW_li = ARENA + 393728;   const bf16* ab_li = ARENA + 1442304;
  const bf16* aW_lo = ARENA + 1442816;  const bf16* ab_lo = ARENA + 1704960;
  const bf16* alt_W = ARENA + 1705472;  const bf16* alt_b = ARENA + 5801472;
  const bf16* ali_W = ARENA + 5809472;  const bf16* ali_b = ARENA + 9905472;
  const bf16* alo_W = ARENA + 9913472;  const bf16* alo_b = ARENA + 14009472;
  const bf16* aua_lin_W  = ARENA + 14017472; const bf16* aua_lin_b  = ARENA + 15041472;
  const bf16* aua_lstm_W = ARENA + 15041984; const bf16* aua_lstm_b = ARENA + 19137984;
  const bf16* aua_out_W  = ARENA + 19145984; const bf16* aua_out_b  = ARENA + 23145984;
  const bf16* apa_lin_W  = ARENA + 23147984; const bf16* apa_lin_b  = ARENA + 24171984;
  const bf16* apa_lstm_W = ARENA + 24172496; const bf16* apa_lstm_b = ARENA + 28268496;
  const bf16* apa_out_W  = ARENA + 28276496; const bf16* apa_out_b  = ARENA + 32276496;

  CvtPtrs cp;
  for (int i = 0; i < 25; ++i) cp.p[i] = (const float*)d_in[6 + i];
  cvt_all<<<dim3(31527), dim3(256), 0, stream>>>(cp, ARENA);

  dim3 blk(256);
  const int NOSPLIT = 1 << 30;

  // ---- user path, M=12288
  gemm_linA32<<<dim3(96,4), blk, 0, stream>>>(u_text,  u_text,  NOSPLIT, aW_lt, ab_lt, X1, 12288, 512, 768, 768, 768, 512);
  gemm_linA32<<<dim3(96,4), blk, 0, stream>>>(u_other, u_other, NOSPLIT, aW_lo, ab_lo, X2, 12288, 512, 512, 512, 512, 512);
  gemm_lstm<<<dim3(96,64), blk, 0, stream>>>(X1, alt_W, alt_b, nullptr, BIG1, 2016, 2016, 0);
  gemm_lstm<<<dim3(96,64), blk, 0, stream>>>(X2, alo_W, alo_b, BIG1,    BIG2, 2016, 2016, 1);
  gemm_lin<<<dim3(96,4), blk, 0, stream>>>(BIG2, aua_lin_W, aua_lin_b, X1, 12288, 512, 2000, 2016, 2000, 512);
  gemm_lstm<<<dim3(96,64), blk, 0, stream>>>(X1, aua_lstm_W, aua_lstm_b, nullptr, BIG1, 2016, 2016, 0);
  meanh<<<dim3(4032), blk, 0, stream>>>(BIG1, Yu);

  // ---- post + center path, M=12800 (rows 12288..12799 = center)
  gemm_linA32<<<dim3(100,4), blk, 0, stream>>>(p_text,  c_text,  96, aW_lt, ab_lt, X1, 12800, 512, 768,  768,  768,  512);
  gemm_linA32<<<dim3(100,4), blk, 0, stream>>>(p_image, c_image, 96, aW_li, ab_li, X2, 12800, 512, 2048, 2048, 2048, 512);
  gemm_lstm<<<dim3(100,64), blk, 0, stream>>>(X1, alt_W, alt_b, nullptr, BIG1, 2016, 2016, 0);
  gemm_lstm<<<dim3(100,64), blk, 0, stream>>>(X2, ali_W, ali_b, BIG1,    BIG2, 2016, 2016, 1);
  // agg uses only the 12288 post-neighbor rows of BIG2
  gemm_lin<<<dim3(96,4), blk, 0, stream>>>(BIG2, apa_lin_W, apa_lin_b, X1, 12288, 512, 2000, 2016, 2000, 512);
  gemm_lstm<<<dim3(96,64), blk, 0, stream>>>(X1, apa_lstm_W, apa_lstm_b, nullptr, BIG1, 2016, 2016, 0);
  meanh<<<dim3(4032), blk, 0, stream>>>(BIG1, Yp);

  // ---- merged agg out-GEMMs (M=512 each, one launch), then attention
  gemm_out_f32<<<dim3(8,16), blk, 0, stream>>>(Yu, Yp, aua_out_W, apa_out_W,
                                               aua_out_b, apa_out_b, UA, PA);
  attn_mix<<<dim3(512), blk, 0, stream>>>(BIG2 + 12288l * 2016, UA, PA, p_att, out, 2016);
}